// Round 13
// baseline (96.182 us; speedup 1.0000x reference)
//
#include <hip/hip_runtime.h>
#include <stdint.h>
#include <math.h>

typedef unsigned long long u64;

// Problem-size caps (H=W=48 grid per reference).
#define FMAXC 4418
#define KRANGES 128
#define BLK 1024
#define TSZ 1024
#define NTMAX 14     // ceil(m/1024) for m=13443
#define PSTR 1056    // pfx stride per tile (1025 slots, padded)

// Monotone float -> uint32 mapping (IEEE total order for non-NaN).
static __device__ __forceinline__ uint32_t f2ord(float f) {
  uint32_t u = __float_as_uint(f);
  return (u & 0x80000000u) ? ~u : (u | 0x80000000u);
}

// Closed-form edge endpoints for the reference grid complex.
static __device__ __forceinline__ void edge_ab(int e, int W, int nh, int nv,
                                               int* a, int* b) {
  if (e < nh) {
    int r = e / (W - 1), c = e - r * (W - 1);
    *a = r * W + c; *b = *a + 1;
  } else if (e < nh + nv) {
    int q = e - nh;
    int r = q / W, c = q - r * W;
    *a = r * W + c; *b = *a + W;
  } else {
    int q = e - nh - nv;
    int r = q / (W - 1), c = q - r * (W - 1);
    *a = r * W + c + 1; *b = (r + 1) * W + c;
  }
}

// Closed-form edge -> adjacent triangles (ids, -1 = none/outer).
static __device__ __forceinline__ void edge_tri(int e, int W, int H, int nh, int nv,
                                                int FH, int* tA, int* tB) {
  if (e < nh) {
    int r = e / (W - 1), c = e - r * (W - 1);
    *tA = (r <= H - 2) ? r * (W - 1) + c : -1;
    *tB = (r >= 1) ? FH + (r - 1) * (W - 1) + c : -1;
  } else if (e < nh + nv) {
    int q = e - nh;
    int r = q / W, c = q - r * W;
    *tA = (c <= W - 2) ? r * (W - 1) + c : -1;
    *tB = (c >= 1) ? FH + r * (W - 1) + (c - 1) : -1;
  } else {
    int q = e - nh - nv;
    int r = q / (W - 1), c = q - r * (W - 1);
    *tA = r * (W - 1) + c;
    *tB = FH + r * (W - 1) + c;
  }
}

// ECL-CC representative with inline path compression.
static __device__ __forceinline__ int rep(volatile int* par, int v) {
  int p = par[v];
  if (p == v) return v;
  int gp = par[p];
  while (p != gp) {
    par[v] = gp;
    v = p; p = gp; gp = par[p];
  }
  return p;
}

// Async min-hook of one edge into a DSU (dual-chain walks + CAS).
static __device__ __forceinline__ void hook(volatile int* vp, uint32_t ab) {
  int va = (int)(ab >> 16), vb = (int)(ab & 0xffffu);
  int pa = vp[va], pb = vp[vb];
  int ga = vp[pa], gb = vp[pb];
  while (pa != ga || pb != gb) {
    if (pa != ga) { vp[va] = ga; va = pa; pa = ga; ga = vp[pa]; }
    if (pb != gb) { vp[vb] = gb; vb = pb; pb = gb; gb = vp[pb]; }
  }
  int u = pa, w = pb;
  while (u != w) {
    if (u < w) { int t = u; u = w; w = t; }
    int old = atomicCAS((int*)&vp[u], u, w);
    if (old == u) break;
    u = rep(vp, old);
    w = rep(vp, w);
  }
}

// Prep + tile-sort: block b owns tile b (1024 simplices). Computes values/keys
// (closed-form vertex sets), zeroes out (grid-strided), bitonic-sorts the tile
// in LDS, writes tilesorted + packed class-prefix (c0 | c1<<16; c2 = pos-c0-c1).
__global__ __launch_bounds__(BLK) void k_prep(
    const float* img, float* vals, u64* keys, u64* tilesorted, uint32_t* pfx,
    float* out, int N, int E, int F, int m, int W, int H, int nh, int nv, int FH,
    int out_n, int NT) {
  __shared__ __align__(16) u64 s[TSZ];
  __shared__ uint32_t sc[TSZ];
  int tid = threadIdx.x, bid = blockIdx.x;
  int gi = bid * BLK + tid;
  for (int i = gi; i < out_n; i += NT * BLK) out[i] = 0.0f;
  int base = bid * TSZ;
  int lim = min(TSZ, m - base);
  u64 key = ~0ull;
  if (gi < m) {
    float v;
    int i = gi;
    if (i < N) {
      v = img[i];
    } else if (i < N + E) {
      int a, b;
      edge_ab(i - N, W, nh, nv, &a, &b);
      v = fmaxf(img[a], img[b]);
    } else {
      int t = i - N - E;
      if (t < FH) {
        int r = t / (W - 1), c = t - r * (W - 1);
        int bse = r * W + c;
        v = fmaxf(img[bse], fmaxf(img[bse + 1], img[bse + W]));
      } else {
        int q = t - FH;
        int r = q / (W - 1), c = q - r * (W - 1);
        int bse = r * W + c;
        v = fmaxf(img[bse + 1], fmaxf(img[bse + W], img[bse + W + 1]));
      }
    }
    vals[i] = v;
    key = ((u64)f2ord(v) << 32) | (u64)(uint32_t)i;
    keys[i] = key;
  }
  s[tid] = key;
  // bitonic sort of the tile (padding ~0ull sorts to the end)
  for (int k = 2; k <= TSZ; k <<= 1) {
    for (int j = k >> 1; j > 0; j >>= 1) {
      __syncthreads();
      int lj = tid ^ j;
      if (lj > tid) {
        u64 a = s[tid], b = s[lj];
        bool up = ((tid & k) == 0);
        if (up ? (a > b) : (a < b)) { s[tid] = b; s[lj] = a; }
      }
    }
  }
  __syncthreads();
  u64 sk = s[tid];
  tilesorted[base + tid] = sk;
  // packed class indicator of the sorted element (c0 low16, c1 high16)
  uint32_t v0 = 0;
  if (tid < lim) {
    int idx = (int)(sk & 0xffffffffu);
    v0 = (idx < N) ? 1u : (idx < N + E ? (1u << 16) : 0u);
  }
  sc[tid] = v0;
  __syncthreads();
  // inclusive Hillis-Steele scan
  for (int off = 1; off < TSZ; off <<= 1) {
    uint32_t t = (tid >= off) ? sc[tid - off] : 0u;
    __syncthreads();
    sc[tid] += t;
    __syncthreads();
  }
  pfx[bid * PSTR + tid] = sc[tid] - v0;          // exclusive
  if (tid == TSZ - 1) pfx[bid * PSTR + TSZ] = sc[tid];  // total slot
}

// Rank: each thread's key lower-bounds all NT sorted tiles (L2-resident,
// register-resident lo[] via constant-trip unrolled loops -> 14-way MLP),
// then reads packed class prefixes. Writes pack directly (no atomics).
__global__ __launch_bounds__(BLK) void k_count(
    const u64* keys, const u64* ts, const uint32_t* pfx, uint32_t* pack,
    int N, int E, int m, int NT) {
  int ki = blockIdx.x * BLK + threadIdx.x;
  if (ki >= m) return;
  u64 k0 = keys[ki];
  int cls0 = (ki < N) ? 0 : (ki < N + E ? 1 : 2);
  int lo[NTMAX];
  #pragma unroll
  for (int t = 0; t < NTMAX; ++t) lo[t] = 0;
  #pragma unroll
  for (int step = TSZ >> 1; step >= 1; step >>= 1) {
    #pragma unroll
    for (int t = 0; t < NTMAX; ++t) {
      if (t < NT) {
        if (ts[(t << 10) + lo[t] + step - 1] < k0) lo[t] += step;
      }
    }
  }
  #pragma unroll
  for (int t = 0; t < NTMAX; ++t) {
    if (t < NT) lo[t] += (ts[(t << 10) + lo[t]] < k0) ? 1 : 0;  // count==TSZ fix
  }
  int tot = 0;
  uint32_t c0 = 0, c1 = 0;
  #pragma unroll
  for (int t = 0; t < NTMAX; ++t) {
    if (t < NT) {
      tot += lo[t];
      uint32_t p = pfx[t * PSTR + lo[t]];
      c0 += p & 0xffffu;
      c1 += p >> 16;
    }
  }
  uint32_t cc = (cls0 == 0) ? c0 : (cls0 == 1 ? c1 : (uint32_t)tot - c0 - c1);
  pack[ki] = (cc << 16) | (uint32_t)tot;
}

// Maps: scatter rank data + build relabeled edge lists with closed-form dual
// adjacency. eAB0[er] = primal endpoints as vranks; eAB1[E-1-er] = dual node
// ids (node = F - trank; outer = 0; smaller = elder).
__global__ __launch_bounds__(256) void k_maps(
    const uint32_t* pack, const float* vals,
    float* vsorted, int* vr_to_rank, int* er_to_rank, int* noderank1,
    uint32_t* eAB0, uint32_t* eAB1,
    int N, int E, int F, int m, int W, int H, int nh, int nv, int FH) {
  int i = blockIdx.x * blockDim.x + threadIdx.x;
  if (i >= m) return;
  uint32_t pk = pack[i];
  int rank = (int)(pk & 0xffffu);
  int cls = (int)(pk >> 16);
  vsorted[rank] = vals[i];
  if (i < N) {
    vr_to_rank[cls] = rank;
  } else if (i < N + E) {
    int e = i - N, er = cls;
    er_to_rank[er] = rank;
    int a, b;
    edge_ab(e, W, nh, nv, &a, &b);
    uint32_t va = pack[a] >> 16, vb = pack[b] >> 16;
    eAB0[er] = (va << 16) | vb;
    int tA, tB;
    edge_tri(e, W, H, nh, nv, FH, &tA, &tB);
    uint32_t na = (tA >= 0) ? ((uint32_t)F - (pack[N + E + tA] >> 16)) : 0u;
    uint32_t nb = (tB >= 0) ? ((uint32_t)F - (pack[N + E + tB] >> 16)) : 0u;
    eAB1[E - 1 - er] = (na << 16) | nb;
  } else {
    noderank1[F - cls] = rank;  // dual node id = F - trank (outer = 0)
  }
}

// Range-parallel elder-rule pairing + emit (proven round-9..12 logic).
__global__ __launch_bounds__(BLK) void k_pair(
    const uint32_t* eAB0, const uint32_t* eAB1,
    const int* vr_to_rank, const int* er_to_rank, const int* noderank1,
    const float* vsorted, float* out, int N, int E, int F, int C, int m) {
  __shared__ __align__(16) int s_par[2 * (FMAXC + 1)];
  __shared__ uint32_t s_rc[64];
  __shared__ int s_ci[64];
  __shared__ int2 s_pairs[64];
  __shared__ int s_cnt[2];
  int tid = threadIdx.x, bid = blockIdx.x;
  int g = bid >> 7;
  int r = bid & (KRANGES - 1);
  int NODES = (g == 0) ? N : (F + 1);
  const uint32_t* eAB = (g == 0) ? eAB0 : eAB1;
  int P = r * C;
  if (P >= E) return;
  int hi = min(P + C, E);
  int nR = hi - P;
  int n1 = (nR + 1) >> 1;
  int n2 = nR - n1;
  int Q = P + n1;
  int* par1 = s_par;
  int* par2 = s_par + (FMAXC + 1);
  volatile int* vp1 = par1;
  volatile int* vp2 = par2;
  for (int x = tid; x < NODES; x += BLK) par1[x] = x;
  __syncthreads();
  for (int i = tid; i < P; i += BLK) hook(vp1, eAB[i]);
  __syncthreads();
  for (int x = tid; x < NODES; x += BLK) {
    int r0 = x;
    while (vp1[r0] != r0) r0 = vp1[r0];
    par1[x] = r0;
  }
  __syncthreads();
  for (int x = tid; x < NODES; x += BLK) par2[x] = par1[x];
  __syncthreads();
  for (int i = tid; i < n1; i += BLK) hook(vp2, eAB[P + i]);
  __syncthreads();
  for (int x = tid; x < NODES; x += BLK) {
    int r0 = x;
    while (vp2[r0] != r0) r0 = vp2[r0];
    par2[x] = r0;
  }
  __syncthreads();
  for (int q = tid; q < nR; q += BLK) {
    int sub = (q >= n1);
    int qq = sub ? q - n1 : q;
    uint32_t ab = eAB[(sub ? Q : P) + qq];
    const int* par = sub ? par2 : par1;
    int ra = par[ab >> 16], rb = par[ab & 0xffffu];
    s_rc[sub * 32 + qq] = ((uint32_t)ra << 16) | (uint32_t)rb;
  }
  __syncthreads();
  if (tid < 128) {
    int sub = tid >> 6;
    int lane = tid & 63;
    int nC = sub ? n2 : n1;
    int ebase = sub ? Q : P;
    uint32_t* rc = s_rc + sub * 32;
    int* ci = s_ci + sub * 32;
    int* par = sub ? par2 : par1;
    uint32_t rr = (lane < nC) ? rc[lane] : 0u;
    int keep = (lane < nC) && ((rr >> 16) != (rr & 0xffffu));
    u64 mask = __ballot(keep);
    if (keep) {
      int idx = __popcll(mask & ((1ull << lane) - 1ull));
      rc[idx] = rr;
      ci[idx] = lane;
    }
    int kc = __popcll(mask);
    if (lane == 0) {
      int c = 0;
      for (int i = 0; i < kc; ++i) {
        uint32_t rr2 = rc[i];
        int x = (int)(rr2 >> 16), y = (int)(rr2 & 0xffffu);
        while (par[x] != x) { par[x] = par[par[x]]; x = par[x]; }
        while (par[y] != y) { par[y] = par[par[y]]; y = par[y]; }
        if (x != y) {
          int die = x > y ? x : y, sur = x < y ? x : y;
          par[die] = sur;
          s_pairs[sub * 32 + c] = make_int2(die, ebase + ci[i]);
          c++;
        }
      }
      s_cnt[sub] = c;
    }
  }
  __syncthreads();
  int c0 = s_cnt[0], c1 = s_cnt[1];
  if (g == 0) {
    for (int q = tid; q < c0 + c1; q += BLK) {
      int2 pq = s_pairs[q < c0 ? q : 32 + (q - c0)];
      int b = vr_to_rank[pq.x], d = er_to_rank[pq.y];
      out[2 * b] = vsorted[b];
      out[2 * b + 1] = vsorted[d];
    }
    if (r == 0 && tid == 0) {
      // essential dim-0 class: rank 0 birth, death = fmax (rank m-1)
      out[0] = vsorted[0];
      out[1] = vsorted[m - 1];
    }
  } else {
    float* o1 = out + 2 * (size_t)m;
    for (int q = tid; q < c0 + c1; q += BLK) {
      int2 pq = s_pairs[q < c0 ? q : 32 + (q - c0)];
      int er = E - 1 - pq.y;
      int b = er_to_rank[er], d = noderank1[pq.x];
      o1[2 * b] = vsorted[b];
      o1[2 * b + 1] = vsorted[d];
    }
  }
}

extern "C" void kernel_launch(void* const* d_in, const int* in_sizes, int n_in,
                              void* d_out, int out_size, void* d_ws, size_t ws_size,
                              hipStream_t stream) {
  const float* img = (const float*)d_in[0];
  int N = in_sizes[0];
  int E = in_sizes[1] / 2;
  int F = in_sizes[2] / 3;
  int m = N + E + F;
  int C = (E + KRANGES - 1) / KRANGES;
  int W = (int)(sqrt((double)N) + 0.5);
  int H = N / W;
  int nh = H * (W - 1);
  int nv = (H - 1) * W;
  int FH = (H - 1) * (W - 1);
  int NT = (m + TSZ - 1) / TSZ;
  float* out = (float*)d_out;

  char* p = (char*)d_ws;
  auto alloc = [&](size_t bytes) { char* r = p; p += (bytes + 255) & ~(size_t)255; return r; };
  u64* keys        = (u64*)alloc((size_t)NT * TSZ * 8);
  u64* tilesorted  = (u64*)alloc((size_t)NT * TSZ * 8);
  uint32_t* pfx    = (uint32_t*)alloc((size_t)NT * PSTR * 4);
  float* vals      = (float*)alloc((size_t)m * 4);
  float* vsorted   = (float*)alloc((size_t)m * 4);
  uint32_t* pack   = (uint32_t*)alloc((size_t)m * 4);
  int* vr_to_rank  = (int*)alloc((size_t)N * 4);
  int* er_to_rank  = (int*)alloc((size_t)E * 4);
  int* noderank1   = (int*)alloc((size_t)(F + 1) * 4);
  uint32_t* eAB0   = (uint32_t*)alloc((size_t)E * 4);
  uint32_t* eAB1   = (uint32_t*)alloc((size_t)E * 4);
  (void)ws_size; (void)n_in;

  k_prep<<<NT, BLK, 0, stream>>>(img, vals, keys, tilesorted, pfx, out,
                                 N, E, F, m, W, H, nh, nv, FH, out_size, NT);
  k_count<<<NT, BLK, 0, stream>>>(keys, tilesorted, pfx, pack, N, E, m, NT);
  k_maps<<<(m + 255) / 256, 256, 0, stream>>>(pack, vals, vsorted,
                                              vr_to_rank, er_to_rank, noderank1,
                                              eAB0, eAB1, N, E, F, m, W, H, nh, nv, FH);
  k_pair<<<2 * KRANGES, BLK, 0, stream>>>(eAB0, eAB1, vr_to_rank, er_to_rank,
                                          noderank1, vsorted, out, N, E, F, C, m);
}

// Round 14
// 48.338 us; speedup vs baseline: 1.9898x; 1.9898x over previous
//
#include <hip/hip_runtime.h>
#include <stdint.h>
#include <math.h>

typedef unsigned long long u64;

// Problem-size caps (H=W=48 grid per reference).
#define FMAXC 4418
#define KRANGES 128
#define BLK 1024
#define TSZ 1024
#define PSTR 1056    // pfx stride per tile (1025 slots, padded)

// Monotone float -> uint32 mapping (IEEE total order for non-NaN).
static __device__ __forceinline__ uint32_t f2ord(float f) {
  uint32_t u = __float_as_uint(f);
  return (u & 0x80000000u) ? ~u : (u | 0x80000000u);
}

// Closed-form edge endpoints for the reference grid complex.
static __device__ __forceinline__ void edge_ab(int e, int W, int nh, int nv,
                                               int* a, int* b) {
  if (e < nh) {
    int r = e / (W - 1), c = e - r * (W - 1);
    *a = r * W + c; *b = *a + 1;
  } else if (e < nh + nv) {
    int q = e - nh;
    int r = q / W, c = q - r * W;
    *a = r * W + c; *b = *a + W;
  } else {
    int q = e - nh - nv;
    int r = q / (W - 1), c = q - r * (W - 1);
    *a = r * W + c + 1; *b = (r + 1) * W + c;
  }
}

// Closed-form edge -> adjacent triangles (ids, -1 = none/outer).
static __device__ __forceinline__ void edge_tri(int e, int W, int H, int nh, int nv,
                                                int FH, int* tA, int* tB) {
  if (e < nh) {
    int r = e / (W - 1), c = e - r * (W - 1);
    *tA = (r <= H - 2) ? r * (W - 1) + c : -1;
    *tB = (r >= 1) ? FH + (r - 1) * (W - 1) + c : -1;
  } else if (e < nh + nv) {
    int q = e - nh;
    int r = q / W, c = q - r * W;
    *tA = (c <= W - 2) ? r * (W - 1) + c : -1;
    *tB = (c >= 1) ? FH + r * (W - 1) + (c - 1) : -1;
  } else {
    int q = e - nh - nv;
    int r = q / (W - 1), c = q - r * (W - 1);
    *tA = r * (W - 1) + c;
    *tB = FH + r * (W - 1) + c;
  }
}

// ECL-CC representative with inline path compression.
static __device__ __forceinline__ int rep(volatile int* par, int v) {
  int p = par[v];
  if (p == v) return v;
  int gp = par[p];
  while (p != gp) {
    par[v] = gp;
    v = p; p = gp; gp = par[p];
  }
  return p;
}

// Async min-hook of one edge into a DSU (dual-chain walks + CAS).
static __device__ __forceinline__ void hook(volatile int* vp, uint32_t ab) {
  int va = (int)(ab >> 16), vb = (int)(ab & 0xffffu);
  int pa = vp[va], pb = vp[vb];
  int ga = vp[pa], gb = vp[pb];
  while (pa != ga || pb != gb) {
    if (pa != ga) { vp[va] = ga; va = pa; pa = ga; ga = vp[pa]; }
    if (pb != gb) { vp[vb] = gb; vb = pb; pb = gb; gb = vp[pb]; }
  }
  int u = pa, w = pb;
  while (u != w) {
    if (u < w) { int t = u; u = w; w = t; }
    int old = atomicCAS((int*)&vp[u], u, w);
    if (old == u) break;
    u = rep(vp, old);
    w = rep(vp, w);
  }
}

// Prep + tile-sort: block b owns tile b (1024 simplices). Computes values/keys
// (closed-form vertex sets), zeroes out+pack, bitonic-sorts the tile in LDS,
// writes tilesorted + packed class-prefix (c0 | c1<<16 below each position).
__global__ __launch_bounds__(BLK) void k_prep(
    const float* img, float* vals, u64* keys, u64* tilesorted, uint32_t* pfx,
    uint32_t* pack, float* out, int N, int E, int F, int m, int W, int H,
    int nh, int nv, int FH, int out_n, int NT) {
  __shared__ __align__(16) u64 s[TSZ];
  __shared__ uint32_t sc[TSZ];
  int tid = threadIdx.x, bid = blockIdx.x;
  int gi = bid * BLK + tid;
  for (int i = gi; i < out_n; i += NT * BLK) out[i] = 0.0f;
  if (gi < m) pack[gi] = 0u;
  int base = bid * TSZ;
  int lim = min(TSZ, m - base);
  u64 key = ~0ull;
  if (gi < m) {
    float v;
    int i = gi;
    if (i < N) {
      v = img[i];
    } else if (i < N + E) {
      int a, b;
      edge_ab(i - N, W, nh, nv, &a, &b);
      v = fmaxf(img[a], img[b]);
    } else {
      int t = i - N - E;
      if (t < FH) {
        int r = t / (W - 1), c = t - r * (W - 1);
        int bse = r * W + c;
        v = fmaxf(img[bse], fmaxf(img[bse + 1], img[bse + W]));
      } else {
        int q = t - FH;
        int r = q / (W - 1), c = q - r * (W - 1);
        int bse = r * W + c;
        v = fmaxf(img[bse + 1], fmaxf(img[bse + W], img[bse + W + 1]));
      }
    }
    vals[i] = v;
    key = ((u64)f2ord(v) << 32) | (u64)(uint32_t)i;
    keys[i] = key;
  }
  s[tid] = key;
  // bitonic sort of the tile (padding ~0ull sorts to the end)
  for (int k = 2; k <= TSZ; k <<= 1) {
    for (int j = k >> 1; j > 0; j >>= 1) {
      __syncthreads();
      int lj = tid ^ j;
      if (lj > tid) {
        u64 a = s[tid], b = s[lj];
        bool up = ((tid & k) == 0);
        if (up ? (a > b) : (a < b)) { s[tid] = b; s[lj] = a; }
      }
    }
  }
  __syncthreads();
  u64 sk = s[tid];
  tilesorted[base + tid] = sk;
  // packed class indicator of the sorted element (c0 low16, c1 high16)
  uint32_t v0 = 0;
  if (tid < lim) {
    int idx = (int)(sk & 0xffffffffu);
    v0 = (idx < N) ? 1u : (idx < N + E ? (1u << 16) : 0u);
  }
  sc[tid] = v0;
  __syncthreads();
  // inclusive Hillis-Steele scan
  for (int off = 1; off < TSZ; off <<= 1) {
    uint32_t t = (tid >= off) ? sc[tid - off] : 0u;
    __syncthreads();
    sc[tid] += t;
    __syncthreads();
  }
  pfx[bid * PSTR + tid] = sc[tid] - v0;          // exclusive
  if (tid == TSZ - 1) pfx[bid * PSTR + TSZ] = sc[tid];  // total slot
}

// Rank: block (tile, keyblock). Stage sorted tile + class prefix in LDS; each
// thread binary-searches its key (11 LDS probes) and accumulates its rank with
// one packed atomicAdd. 196 blocks -> latency hidden by occupancy.
__global__ __launch_bounds__(BLK) void k_count(
    const u64* keys, const u64* ts, const uint32_t* pfx, uint32_t* pack,
    int N, int E, int m) {
  __shared__ __align__(16) u64 s[TSZ];
  __shared__ uint32_t sp[TSZ + 1];
  int tid = threadIdx.x;
  int t = blockIdx.x;
  s[tid] = ts[(t << 10) + tid];
  sp[tid] = pfx[t * PSTR + tid];
  if (tid == 0) sp[TSZ] = pfx[t * PSTR + TSZ];
  __syncthreads();
  int ki = blockIdx.y * BLK + tid;
  if (ki >= m) return;
  u64 k0 = keys[ki];
  int cls0 = (ki < N) ? 0 : (ki < N + E ? 1 : 2);
  int lo = 0;
  #pragma unroll
  for (int step = TSZ >> 1; step >= 1; step >>= 1) {
    if (s[lo + step - 1] < k0) lo += step;
  }
  lo += (s[lo] < k0) ? 1 : 0;     // off-by-one fix: count==TSZ case
  uint32_t p = sp[lo];
  uint32_t c0 = p & 0xffffu, c1 = p >> 16;
  uint32_t cc = (cls0 == 0) ? c0 : (cls0 == 1 ? c1 : (uint32_t)lo - c0 - c1);
  atomicAdd(&pack[ki], (cc << 16) | (uint32_t)lo);
}

// Maps: scatter rank data + build relabeled edge lists with closed-form dual
// adjacency. eAB0[er] = primal endpoints as vranks; eAB1[E-1-er] = dual node
// ids (node = F - trank; outer = 0; smaller = elder).
__global__ __launch_bounds__(256) void k_maps(
    const uint32_t* pack, const float* vals,
    float* vsorted, int* vr_to_rank, int* er_to_rank, int* noderank1,
    uint32_t* eAB0, uint32_t* eAB1,
    int N, int E, int F, int m, int W, int H, int nh, int nv, int FH) {
  int i = blockIdx.x * blockDim.x + threadIdx.x;
  if (i >= m) return;
  uint32_t pk = pack[i];
  int rank = (int)(pk & 0xffffu);
  int cls = (int)(pk >> 16);
  vsorted[rank] = vals[i];
  if (i < N) {
    vr_to_rank[cls] = rank;
  } else if (i < N + E) {
    int e = i - N, er = cls;
    er_to_rank[er] = rank;
    int a, b;
    edge_ab(e, W, nh, nv, &a, &b);
    uint32_t va = pack[a] >> 16, vb = pack[b] >> 16;
    eAB0[er] = (va << 16) | vb;
    int tA, tB;
    edge_tri(e, W, H, nh, nv, FH, &tA, &tB);
    uint32_t na = (tA >= 0) ? ((uint32_t)F - (pack[N + E + tA] >> 16)) : 0u;
    uint32_t nb = (tB >= 0) ? ((uint32_t)F - (pack[N + E + tB] >> 16)) : 0u;
    eAB1[E - 1 - er] = (na << 16) | nb;
  } else {
    noderank1[F - cls] = rank;  // dual node id = F - trank (outer = 0)
  }
}

// Range-parallel elder-rule pairing + emit (proven round-9..13 logic).
__global__ __launch_bounds__(BLK) void k_pair(
    const uint32_t* eAB0, const uint32_t* eAB1,
    const int* vr_to_rank, const int* er_to_rank, const int* noderank1,
    const float* vsorted, float* out, int N, int E, int F, int C, int m) {
  __shared__ __align__(16) int s_par[2 * (FMAXC + 1)];
  __shared__ uint32_t s_rc[64];
  __shared__ int s_ci[64];
  __shared__ int2 s_pairs[64];
  __shared__ int s_cnt[2];
  int tid = threadIdx.x, bid = blockIdx.x;
  int g = bid >> 7;
  int r = bid & (KRANGES - 1);
  int NODES = (g == 0) ? N : (F + 1);
  const uint32_t* eAB = (g == 0) ? eAB0 : eAB1;
  int P = r * C;
  if (P >= E) return;
  int hi = min(P + C, E);
  int nR = hi - P;
  int n1 = (nR + 1) >> 1;
  int n2 = nR - n1;
  int Q = P + n1;
  int* par1 = s_par;
  int* par2 = s_par + (FMAXC + 1);
  volatile int* vp1 = par1;
  volatile int* vp2 = par2;
  for (int x = tid; x < NODES; x += BLK) par1[x] = x;
  __syncthreads();
  for (int i = tid; i < P; i += BLK) hook(vp1, eAB[i]);
  __syncthreads();
  for (int x = tid; x < NODES; x += BLK) {
    int r0 = x;
    while (vp1[r0] != r0) r0 = vp1[r0];
    par1[x] = r0;
  }
  __syncthreads();
  for (int x = tid; x < NODES; x += BLK) par2[x] = par1[x];
  __syncthreads();
  for (int i = tid; i < n1; i += BLK) hook(vp2, eAB[P + i]);
  __syncthreads();
  for (int x = tid; x < NODES; x += BLK) {
    int r0 = x;
    while (vp2[r0] != r0) r0 = vp2[r0];
    par2[x] = r0;
  }
  __syncthreads();
  for (int q = tid; q < nR; q += BLK) {
    int sub = (q >= n1);
    int qq = sub ? q - n1 : q;
    uint32_t ab = eAB[(sub ? Q : P) + qq];
    const int* par = sub ? par2 : par1;
    int ra = par[ab >> 16], rb = par[ab & 0xffffu];
    s_rc[sub * 32 + qq] = ((uint32_t)ra << 16) | (uint32_t)rb;
  }
  __syncthreads();
  if (tid < 128) {
    int sub = tid >> 6;
    int lane = tid & 63;
    int nC = sub ? n2 : n1;
    int ebase = sub ? Q : P;
    uint32_t* rc = s_rc + sub * 32;
    int* ci = s_ci + sub * 32;
    int* par = sub ? par2 : par1;
    uint32_t rr = (lane < nC) ? rc[lane] : 0u;
    int keep = (lane < nC) && ((rr >> 16) != (rr & 0xffffu));
    u64 mask = __ballot(keep);
    if (keep) {
      int idx = __popcll(mask & ((1ull << lane) - 1ull));
      rc[idx] = rr;
      ci[idx] = lane;
    }
    int kc = __popcll(mask);
    if (lane == 0) {
      int c = 0;
      for (int i = 0; i < kc; ++i) {
        uint32_t rr2 = rc[i];
        int x = (int)(rr2 >> 16), y = (int)(rr2 & 0xffffu);
        while (par[x] != x) { par[x] = par[par[x]]; x = par[x]; }
        while (par[y] != y) { par[y] = par[par[y]]; y = par[y]; }
        if (x != y) {
          int die = x > y ? x : y, sur = x < y ? x : y;
          par[die] = sur;
          s_pairs[sub * 32 + c] = make_int2(die, ebase + ci[i]);
          c++;
        }
      }
      s_cnt[sub] = c;
    }
  }
  __syncthreads();
  int c0 = s_cnt[0], c1 = s_cnt[1];
  if (g == 0) {
    for (int q = tid; q < c0 + c1; q += BLK) {
      int2 pq = s_pairs[q < c0 ? q : 32 + (q - c0)];
      int b = vr_to_rank[pq.x], d = er_to_rank[pq.y];
      out[2 * b] = vsorted[b];
      out[2 * b + 1] = vsorted[d];
    }
    if (r == 0 && tid == 0) {
      // essential dim-0 class: rank 0 birth, death = fmax (rank m-1)
      out[0] = vsorted[0];
      out[1] = vsorted[m - 1];
    }
  } else {
    float* o1 = out + 2 * (size_t)m;
    for (int q = tid; q < c0 + c1; q += BLK) {
      int2 pq = s_pairs[q < c0 ? q : 32 + (q - c0)];
      int er = E - 1 - pq.y;
      int b = er_to_rank[er], d = noderank1[pq.x];
      o1[2 * b] = vsorted[b];
      o1[2 * b + 1] = vsorted[d];
    }
  }
}

extern "C" void kernel_launch(void* const* d_in, const int* in_sizes, int n_in,
                              void* d_out, int out_size, void* d_ws, size_t ws_size,
                              hipStream_t stream) {
  const float* img = (const float*)d_in[0];
  int N = in_sizes[0];
  int E = in_sizes[1] / 2;
  int F = in_sizes[2] / 3;
  int m = N + E + F;
  int C = (E + KRANGES - 1) / KRANGES;
  int W = (int)(sqrt((double)N) + 0.5);
  int H = N / W;
  int nh = H * (W - 1);
  int nv = (H - 1) * W;
  int FH = (H - 1) * (W - 1);
  int NT = (m + TSZ - 1) / TSZ;
  float* out = (float*)d_out;

  char* p = (char*)d_ws;
  auto alloc = [&](size_t bytes) { char* r = p; p += (bytes + 255) & ~(size_t)255; return r; };
  u64* keys        = (u64*)alloc((size_t)NT * TSZ * 8);
  u64* tilesorted  = (u64*)alloc((size_t)NT * TSZ * 8);
  uint32_t* pfx    = (uint32_t*)alloc((size_t)NT * PSTR * 4);
  float* vals      = (float*)alloc((size_t)m * 4);
  float* vsorted   = (float*)alloc((size_t)m * 4);
  uint32_t* pack   = (uint32_t*)alloc((size_t)m * 4);
  int* vr_to_rank  = (int*)alloc((size_t)N * 4);
  int* er_to_rank  = (int*)alloc((size_t)E * 4);
  int* noderank1   = (int*)alloc((size_t)(F + 1) * 4);
  uint32_t* eAB0   = (uint32_t*)alloc((size_t)E * 4);
  uint32_t* eAB1   = (uint32_t*)alloc((size_t)E * 4);
  (void)ws_size; (void)n_in;

  k_prep<<<NT, BLK, 0, stream>>>(img, vals, keys, tilesorted, pfx, pack, out,
                                 N, E, F, m, W, H, nh, nv, FH, out_size, NT);
  dim3 cg(NT, NT);
  k_count<<<cg, BLK, 0, stream>>>(keys, tilesorted, pfx, pack, N, E, m);
  k_maps<<<(m + 255) / 256, 256, 0, stream>>>(pack, vals, vsorted,
                                              vr_to_rank, er_to_rank, noderank1,
                                              eAB0, eAB1, N, E, F, m, W, H, nh, nv, FH);
  k_pair<<<2 * KRANGES, BLK, 0, stream>>>(eAB0, eAB1, vr_to_rank, er_to_rank,
                                          noderank1, vsorted, out, N, E, F, C, m);
}

// Round 15
// 45.674 us; speedup vs baseline: 2.1058x; 1.0583x over previous
//
#include <hip/hip_runtime.h>
#include <stdint.h>
#include <math.h>

typedef unsigned long long u64;

// Problem-size caps (H=W=48 grid per reference).
#define FMAXC 4418
#define KRANGES 128
#define BLK 1024
#define TSZ 1024
#define PSTR 1056    // pfx stride per tile (1025 slots, padded)

// Monotone float -> uint32 mapping (IEEE total order for non-NaN).
static __device__ __forceinline__ uint32_t f2ord(float f) {
  uint32_t u = __float_as_uint(f);
  return (u & 0x80000000u) ? ~u : (u | 0x80000000u);
}

static __device__ __forceinline__ u64 shfl_xor_u64(u64 x, int msk) {
  int lo = __shfl_xor((int)(uint32_t)x, msk, 64);
  int hi = __shfl_xor((int)(uint32_t)(x >> 32), msk, 64);
  return ((u64)(uint32_t)hi << 32) | (uint32_t)lo;
}

// Closed-form edge endpoints for the reference grid complex.
static __device__ __forceinline__ void edge_ab(int e, int W, int nh, int nv,
                                               int* a, int* b) {
  if (e < nh) {
    int r = e / (W - 1), c = e - r * (W - 1);
    *a = r * W + c; *b = *a + 1;
  } else if (e < nh + nv) {
    int q = e - nh;
    int r = q / W, c = q - r * W;
    *a = r * W + c; *b = *a + W;
  } else {
    int q = e - nh - nv;
    int r = q / (W - 1), c = q - r * (W - 1);
    *a = r * W + c + 1; *b = (r + 1) * W + c;
  }
}

// Closed-form edge -> adjacent triangles (ids, -1 = none/outer).
static __device__ __forceinline__ void edge_tri(int e, int W, int H, int nh, int nv,
                                                int FH, int* tA, int* tB) {
  if (e < nh) {
    int r = e / (W - 1), c = e - r * (W - 1);
    *tA = (r <= H - 2) ? r * (W - 1) + c : -1;
    *tB = (r >= 1) ? FH + (r - 1) * (W - 1) + c : -1;
  } else if (e < nh + nv) {
    int q = e - nh;
    int r = q / W, c = q - r * W;
    *tA = (c <= W - 2) ? r * (W - 1) + c : -1;
    *tB = (c >= 1) ? FH + r * (W - 1) + (c - 1) : -1;
  } else {
    int q = e - nh - nv;
    int r = q / (W - 1), c = q - r * (W - 1);
    *tA = r * (W - 1) + c;
    *tB = FH + r * (W - 1) + c;
  }
}

// ECL-CC representative with inline path compression.
static __device__ __forceinline__ int rep(volatile int* par, int v) {
  int p = par[v];
  if (p == v) return v;
  int gp = par[p];
  while (p != gp) {
    par[v] = gp;
    v = p; p = gp; gp = par[p];
  }
  return p;
}

// Async min-hook of one edge into a DSU (dual-chain walks + CAS).
static __device__ __forceinline__ void hook(volatile int* vp, uint32_t ab) {
  int va = (int)(ab >> 16), vb = (int)(ab & 0xffffu);
  int pa = vp[va], pb = vp[vb];
  int ga = vp[pa], gb = vp[pb];
  while (pa != ga || pb != gb) {
    if (pa != ga) { vp[va] = ga; va = pa; pa = ga; ga = vp[pa]; }
    if (pb != gb) { vp[vb] = gb; vb = pb; pb = gb; gb = vp[pb]; }
  }
  int u = pa, w = pb;
  while (u != w) {
    if (u < w) { int t = u; u = w; w = t; }
    int old = atomicCAS((int*)&vp[u], u, w);
    if (old == u) break;
    u = rep(vp, old);
    w = rep(vp, w);
  }
}

// Prep + tile-sort: block b owns tile b (1024 simplices). Computes values/keys
// (closed-form vertex sets), zeroes out+pack, sorts the tile with a hybrid
// shfl/LDS bitonic network (register-resident; only j>=64 substeps use LDS),
// writes tilesorted + packed class-prefix (c0 | c1<<16 below each position).
__global__ __launch_bounds__(BLK) void k_prep(
    const float* img, float* vals, u64* keys, u64* tilesorted, uint32_t* pfx,
    uint32_t* pack, float* out, int N, int E, int F, int m, int W, int H,
    int nh, int nv, int FH, int out_n, int NT) {
  __shared__ __align__(16) u64 s[TSZ];
  __shared__ uint32_t wsum[16];
  int tid = threadIdx.x, bid = blockIdx.x;
  int lane = tid & 63, wid = tid >> 6;
  int gi = bid * BLK + tid;
  for (int i = gi; i < out_n; i += NT * BLK) out[i] = 0.0f;
  if (gi < m) pack[gi] = 0u;
  int base = bid * TSZ;
  int lim = min(TSZ, m - base);
  u64 v = ~0ull;
  if (gi < m) {
    float val;
    int i = gi;
    if (i < N) {
      val = img[i];
    } else if (i < N + E) {
      int a, b;
      edge_ab(i - N, W, nh, nv, &a, &b);
      val = fmaxf(img[a], img[b]);
    } else {
      int t = i - N - E;
      if (t < FH) {
        int r = t / (W - 1), c = t - r * (W - 1);
        int bse = r * W + c;
        val = fmaxf(img[bse], fmaxf(img[bse + 1], img[bse + W]));
      } else {
        int q = t - FH;
        int r = q / (W - 1), c = q - r * (W - 1);
        int bse = r * W + c;
        val = fmaxf(img[bse + 1], fmaxf(img[bse + W], img[bse + W + 1]));
      }
    }
    vals[i] = val;
    v = ((u64)f2ord(val) << 32) | (u64)(uint32_t)i;
    keys[i] = v;
  }
  // hybrid bitonic sort: value in register; takeMin = ((tid&j)==0)==((tid&k)==0)
  for (int k = 2; k <= TSZ; k <<= 1) {
    for (int j = k >> 1; j > 0; j >>= 1) {
      bool asc = ((tid & k) == 0);
      if (j >= 64) {
        s[tid] = v;
        __syncthreads();
        u64 u = s[tid ^ j];
        bool takeMin = (((tid & j) == 0) == asc);
        v = takeMin ? (v < u ? v : u) : (v > u ? v : u);
        __syncthreads();
      } else {
        u64 u = shfl_xor_u64(v, j);
        bool takeMin = (((tid & j) == 0) == asc);
        v = takeMin ? (v < u ? v : u) : (v > u ? v : u);
      }
    }
  }
  tilesorted[base + tid] = v;
  // packed class indicator of the sorted element (c0 low16, c1 high16);
  // pads (~0ull) sorted to positions >= lim.
  uint32_t v0 = 0;
  if (tid < lim) {
    int idx = (int)(v & 0xffffffffu);
    v0 = (idx < N) ? 1u : (idx < N + E ? (1u << 16) : 0u);
  }
  // inclusive scan: wave shfl scan + cross-wave combine
  uint32_t sv = v0;
  #pragma unroll
  for (int off = 1; off < 64; off <<= 1) {
    uint32_t t = (uint32_t)__shfl_up((int)sv, off, 64);
    if (lane >= off) sv += t;
  }
  if (lane == 63) wsum[wid] = sv;
  __syncthreads();
  if (tid < 16) {
    uint32_t t = wsum[tid];
    #pragma unroll
    for (int off = 1; off < 16; off <<= 1) {
      uint32_t u2 = (uint32_t)__shfl_up((int)t, off, 64);
      if (tid >= off) t += u2;
    }
    wsum[tid] = t;
  }
  __syncthreads();
  uint32_t incl = sv + (wid > 0 ? wsum[wid - 1] : 0u);
  pfx[bid * PSTR + tid] = incl - v0;             // exclusive
  if (tid == TSZ - 1) pfx[bid * PSTR + TSZ] = incl;  // total slot
}

// Rank: block (tile, keyblock). Stage sorted tile + class prefix in LDS; each
// thread binary-searches its key (11 LDS probes) and accumulates its rank with
// one packed atomicAdd. 196 blocks -> latency hidden by occupancy.
__global__ __launch_bounds__(BLK) void k_count(
    const u64* keys, const u64* ts, const uint32_t* pfx, uint32_t* pack,
    int N, int E, int m) {
  __shared__ __align__(16) u64 s[TSZ];
  __shared__ uint32_t sp[TSZ + 1];
  int tid = threadIdx.x;
  int t = blockIdx.x;
  s[tid] = ts[(t << 10) + tid];
  sp[tid] = pfx[t * PSTR + tid];
  if (tid == 0) sp[TSZ] = pfx[t * PSTR + TSZ];
  __syncthreads();
  int ki = blockIdx.y * BLK + tid;
  if (ki >= m) return;
  u64 k0 = keys[ki];
  int cls0 = (ki < N) ? 0 : (ki < N + E ? 1 : 2);
  int lo = 0;
  #pragma unroll
  for (int step = TSZ >> 1; step >= 1; step >>= 1) {
    if (s[lo + step - 1] < k0) lo += step;
  }
  lo += (s[lo] < k0) ? 1 : 0;     // off-by-one fix: count==TSZ case
  uint32_t p = sp[lo];
  uint32_t c0 = p & 0xffffu, c1 = p >> 16;
  uint32_t cc = (cls0 == 0) ? c0 : (cls0 == 1 ? c1 : (uint32_t)lo - c0 - c1);
  atomicAdd(&pack[ki], (cc << 16) | (uint32_t)lo);
}

// Maps: scatter rank data + build relabeled edge lists with closed-form dual
// adjacency. eAB0[er] = primal endpoints as vranks; eAB1[E-1-er] = dual node
// ids (node = F - trank; outer = 0; smaller = elder).
__global__ __launch_bounds__(256) void k_maps(
    const uint32_t* pack, const float* vals,
    float* vsorted, int* vr_to_rank, int* er_to_rank, int* noderank1,
    uint32_t* eAB0, uint32_t* eAB1,
    int N, int E, int F, int m, int W, int H, int nh, int nv, int FH) {
  int i = blockIdx.x * blockDim.x + threadIdx.x;
  if (i >= m) return;
  uint32_t pk = pack[i];
  int rank = (int)(pk & 0xffffu);
  int cls = (int)(pk >> 16);
  vsorted[rank] = vals[i];
  if (i < N) {
    vr_to_rank[cls] = rank;
  } else if (i < N + E) {
    int e = i - N, er = cls;
    er_to_rank[er] = rank;
    int a, b;
    edge_ab(e, W, nh, nv, &a, &b);
    uint32_t va = pack[a] >> 16, vb = pack[b] >> 16;
    eAB0[er] = (va << 16) | vb;
    int tA, tB;
    edge_tri(e, W, H, nh, nv, FH, &tA, &tB);
    uint32_t na = (tA >= 0) ? ((uint32_t)F - (pack[N + E + tA] >> 16)) : 0u;
    uint32_t nb = (tB >= 0) ? ((uint32_t)F - (pack[N + E + tB] >> 16)) : 0u;
    eAB1[E - 1 - er] = (na << 16) | nb;
  } else {
    noderank1[F - cls] = rank;  // dual node id = F - trank (outer = 0)
  }
}

// Range-parallel elder-rule pairing + emit (proven round-9..14 logic).
__global__ __launch_bounds__(BLK) void k_pair(
    const uint32_t* eAB0, const uint32_t* eAB1,
    const int* vr_to_rank, const int* er_to_rank, const int* noderank1,
    const float* vsorted, float* out, int N, int E, int F, int C, int m) {
  __shared__ __align__(16) int s_par[2 * (FMAXC + 1)];
  __shared__ uint32_t s_rc[64];
  __shared__ int s_ci[64];
  __shared__ int2 s_pairs[64];
  __shared__ int s_cnt[2];
  int tid = threadIdx.x, bid = blockIdx.x;
  int g = bid >> 7;
  int r = bid & (KRANGES - 1);
  int NODES = (g == 0) ? N : (F + 1);
  const uint32_t* eAB = (g == 0) ? eAB0 : eAB1;
  int P = r * C;
  if (P >= E) return;
  int hi = min(P + C, E);
  int nR = hi - P;
  int n1 = (nR + 1) >> 1;
  int n2 = nR - n1;
  int Q = P + n1;
  int* par1 = s_par;
  int* par2 = s_par + (FMAXC + 1);
  volatile int* vp1 = par1;
  volatile int* vp2 = par2;
  for (int x = tid; x < NODES; x += BLK) par1[x] = x;
  __syncthreads();
  for (int i = tid; i < P; i += BLK) hook(vp1, eAB[i]);
  __syncthreads();
  for (int x = tid; x < NODES; x += BLK) {
    int r0 = x;
    while (vp1[r0] != r0) r0 = vp1[r0];
    par1[x] = r0;
  }
  __syncthreads();
  for (int x = tid; x < NODES; x += BLK) par2[x] = par1[x];
  __syncthreads();
  for (int i = tid; i < n1; i += BLK) hook(vp2, eAB[P + i]);
  __syncthreads();
  for (int x = tid; x < NODES; x += BLK) {
    int r0 = x;
    while (vp2[r0] != r0) r0 = vp2[r0];
    par2[x] = r0;
  }
  __syncthreads();
  for (int q = tid; q < nR; q += BLK) {
    int sub = (q >= n1);
    int qq = sub ? q - n1 : q;
    uint32_t ab = eAB[(sub ? Q : P) + qq];
    const int* par = sub ? par2 : par1;
    int ra = par[ab >> 16], rb = par[ab & 0xffffu];
    s_rc[sub * 32 + qq] = ((uint32_t)ra << 16) | (uint32_t)rb;
  }
  __syncthreads();
  if (tid < 128) {
    int sub = tid >> 6;
    int lane = tid & 63;
    int nC = sub ? n2 : n1;
    int ebase = sub ? Q : P;
    uint32_t* rc = s_rc + sub * 32;
    int* ci = s_ci + sub * 32;
    int* par = sub ? par2 : par1;
    uint32_t rr = (lane < nC) ? rc[lane] : 0u;
    int keep = (lane < nC) && ((rr >> 16) != (rr & 0xffffu));
    u64 mask = __ballot(keep);
    if (keep) {
      int idx = __popcll(mask & ((1ull << lane) - 1ull));
      rc[idx] = rr;
      ci[idx] = lane;
    }
    int kc = __popcll(mask);
    if (lane == 0) {
      int c = 0;
      for (int i = 0; i < kc; ++i) {
        uint32_t rr2 = rc[i];
        int x = (int)(rr2 >> 16), y = (int)(rr2 & 0xffffu);
        while (par[x] != x) { par[x] = par[par[x]]; x = par[x]; }
        while (par[y] != y) { par[y] = par[par[y]]; y = par[y]; }
        if (x != y) {
          int die = x > y ? x : y, sur = x < y ? x : y;
          par[die] = sur;
          s_pairs[sub * 32 + c] = make_int2(die, ebase + ci[i]);
          c++;
        }
      }
      s_cnt[sub] = c;
    }
  }
  __syncthreads();
  int c0 = s_cnt[0], c1 = s_cnt[1];
  if (g == 0) {
    for (int q = tid; q < c0 + c1; q += BLK) {
      int2 pq = s_pairs[q < c0 ? q : 32 + (q - c0)];
      int b = vr_to_rank[pq.x], d = er_to_rank[pq.y];
      out[2 * b] = vsorted[b];
      out[2 * b + 1] = vsorted[d];
    }
    if (r == 0 && tid == 0) {
      // essential dim-0 class: rank 0 birth, death = fmax (rank m-1)
      out[0] = vsorted[0];
      out[1] = vsorted[m - 1];
    }
  } else {
    float* o1 = out + 2 * (size_t)m;
    for (int q = tid; q < c0 + c1; q += BLK) {
      int2 pq = s_pairs[q < c0 ? q : 32 + (q - c0)];
      int er = E - 1 - pq.y;
      int b = er_to_rank[er], d = noderank1[pq.x];
      o1[2 * b] = vsorted[b];
      o1[2 * b + 1] = vsorted[d];
    }
  }
}

extern "C" void kernel_launch(void* const* d_in, const int* in_sizes, int n_in,
                              void* d_out, int out_size, void* d_ws, size_t ws_size,
                              hipStream_t stream) {
  const float* img = (const float*)d_in[0];
  int N = in_sizes[0];
  int E = in_sizes[1] / 2;
  int F = in_sizes[2] / 3;
  int m = N + E + F;
  int C = (E + KRANGES - 1) / KRANGES;
  int W = (int)(sqrt((double)N) + 0.5);
  int H = N / W;
  int nh = H * (W - 1);
  int nv = (H - 1) * W;
  int FH = (H - 1) * (W - 1);
  int NT = (m + TSZ - 1) / TSZ;
  float* out = (float*)d_out;

  char* p = (char*)d_ws;
  auto alloc = [&](size_t bytes) { char* r = p; p += (bytes + 255) & ~(size_t)255; return r; };
  u64* keys        = (u64*)alloc((size_t)NT * TSZ * 8);
  u64* tilesorted  = (u64*)alloc((size_t)NT * TSZ * 8);
  uint32_t* pfx    = (uint32_t*)alloc((size_t)NT * PSTR * 4);
  float* vals      = (float*)alloc((size_t)m * 4);
  float* vsorted   = (float*)alloc((size_t)m * 4);
  uint32_t* pack   = (uint32_t*)alloc((size_t)m * 4);
  int* vr_to_rank  = (int*)alloc((size_t)N * 4);
  int* er_to_rank  = (int*)alloc((size_t)E * 4);
  int* noderank1   = (int*)alloc((size_t)(F + 1) * 4);
  uint32_t* eAB0   = (uint32_t*)alloc((size_t)E * 4);
  uint32_t* eAB1   = (uint32_t*)alloc((size_t)E * 4);
  (void)ws_size; (void)n_in;

  k_prep<<<NT, BLK, 0, stream>>>(img, vals, keys, tilesorted, pfx, pack, out,
                                 N, E, F, m, W, H, nh, nv, FH, out_size, NT);
  dim3 cg(NT, NT);
  k_count<<<cg, BLK, 0, stream>>>(keys, tilesorted, pfx, pack, N, E, m);
  k_maps<<<(m + 255) / 256, 256, 0, stream>>>(pack, vals, vsorted,
                                              vr_to_rank, er_to_rank, noderank1,
                                              eAB0, eAB1, N, E, F, m, W, H, nh, nv, FH);
  k_pair<<<2 * KRANGES, BLK, 0, stream>>>(eAB0, eAB1, vr_to_rank, er_to_rank,
                                          noderank1, vsorted, out, N, E, F, C, m);
}

// Round 16
// 45.227 us; speedup vs baseline: 2.1266x; 1.0099x over previous
//
#include <hip/hip_runtime.h>
#include <stdint.h>
#include <math.h>

typedef unsigned long long u64;

// Problem-size caps (H=W=48 grid per reference).
#define FMAXC 4418
#define KRANGES 256
#define BLK 1024
#define TSZ 1024
#define PSTR 1056    // pfx stride per tile (1025 slots, padded)

// Monotone float -> uint32 mapping (IEEE total order for non-NaN).
static __device__ __forceinline__ uint32_t f2ord(float f) {
  uint32_t u = __float_as_uint(f);
  return (u & 0x80000000u) ? ~u : (u | 0x80000000u);
}

static __device__ __forceinline__ u64 shfl_xor_u64(u64 x, int msk) {
  int lo = __shfl_xor((int)(uint32_t)x, msk, 64);
  int hi = __shfl_xor((int)(uint32_t)(x >> 32), msk, 64);
  return ((u64)(uint32_t)hi << 32) | (uint32_t)lo;
}

// Closed-form edge endpoints for the reference grid complex.
static __device__ __forceinline__ void edge_ab(int e, int W, int nh, int nv,
                                               int* a, int* b) {
  if (e < nh) {
    int r = e / (W - 1), c = e - r * (W - 1);
    *a = r * W + c; *b = *a + 1;
  } else if (e < nh + nv) {
    int q = e - nh;
    int r = q / W, c = q - r * W;
    *a = r * W + c; *b = *a + W;
  } else {
    int q = e - nh - nv;
    int r = q / (W - 1), c = q - r * (W - 1);
    *a = r * W + c + 1; *b = (r + 1) * W + c;
  }
}

// Closed-form edge -> adjacent triangles (ids, -1 = none/outer).
static __device__ __forceinline__ void edge_tri(int e, int W, int H, int nh, int nv,
                                                int FH, int* tA, int* tB) {
  if (e < nh) {
    int r = e / (W - 1), c = e - r * (W - 1);
    *tA = (r <= H - 2) ? r * (W - 1) + c : -1;
    *tB = (r >= 1) ? FH + (r - 1) * (W - 1) + c : -1;
  } else if (e < nh + nv) {
    int q = e - nh;
    int r = q / W, c = q - r * W;
    *tA = (c <= W - 2) ? r * (W - 1) + c : -1;
    *tB = (c >= 1) ? FH + r * (W - 1) + (c - 1) : -1;
  } else {
    int q = e - nh - nv;
    int r = q / (W - 1), c = q - r * (W - 1);
    *tA = r * (W - 1) + c;
    *tB = FH + r * (W - 1) + c;
  }
}

// ECL-CC representative with inline path compression.
static __device__ __forceinline__ int rep(volatile int* par, int v) {
  int p = par[v];
  if (p == v) return v;
  int gp = par[p];
  while (p != gp) {
    par[v] = gp;
    v = p; p = gp; gp = par[p];
  }
  return p;
}

// Async min-hook of one edge into a DSU (dual-chain walks + CAS).
static __device__ __forceinline__ void hook(volatile int* vp, uint32_t ab) {
  int va = (int)(ab >> 16), vb = (int)(ab & 0xffffu);
  int pa = vp[va], pb = vp[vb];
  int ga = vp[pa], gb = vp[pb];
  while (pa != ga || pb != gb) {
    if (pa != ga) { vp[va] = ga; va = pa; pa = ga; ga = vp[pa]; }
    if (pb != gb) { vp[vb] = gb; vb = pb; pb = gb; gb = vp[pb]; }
  }
  int u = pa, w = pb;
  while (u != w) {
    if (u < w) { int t = u; u = w; w = t; }
    int old = atomicCAS((int*)&vp[u], u, w);
    if (old == u) break;
    u = rep(vp, old);
    w = rep(vp, w);
  }
}

// Prep + tile-sort: block b owns tile b (1024 simplices). Computes values/keys
// (closed-form vertex sets), zeroes out+pack, sorts the tile with a hybrid
// shfl/LDS bitonic network (double-buffered LDS -> 1 barrier per LDS substep),
// writes tilesorted + packed class-prefix (c0 | c1<<16 below each position).
__global__ __launch_bounds__(BLK) void k_prep(
    const float* img, float* vals, u64* keys, u64* tilesorted, uint32_t* pfx,
    uint32_t* pack, float* out, int N, int E, int F, int m, int W, int H,
    int nh, int nv, int FH, int out_n, int NT) {
  __shared__ __align__(16) u64 s[2][TSZ];
  __shared__ uint32_t wsum[16];
  int tid = threadIdx.x, bid = blockIdx.x;
  int lane = tid & 63, wid = tid >> 6;
  int gi = bid * BLK + tid;
  for (int i = gi; i < out_n; i += NT * BLK) out[i] = 0.0f;
  if (gi < m) pack[gi] = 0u;
  int base = bid * TSZ;
  int lim = min(TSZ, m - base);
  u64 v = ~0ull;
  if (gi < m) {
    float val;
    int i = gi;
    if (i < N) {
      val = img[i];
    } else if (i < N + E) {
      int a, b;
      edge_ab(i - N, W, nh, nv, &a, &b);
      val = fmaxf(img[a], img[b]);
    } else {
      int t = i - N - E;
      if (t < FH) {
        int r = t / (W - 1), c = t - r * (W - 1);
        int bse = r * W + c;
        val = fmaxf(img[bse], fmaxf(img[bse + 1], img[bse + W]));
      } else {
        int q = t - FH;
        int r = q / (W - 1), c = q - r * (W - 1);
        int bse = r * W + c;
        val = fmaxf(img[bse + 1], fmaxf(img[bse + W], img[bse + W + 1]));
      }
    }
    vals[i] = val;
    v = ((u64)f2ord(val) << 32) | (u64)(uint32_t)i;
    keys[i] = v;
  }
  // hybrid bitonic sort: value in register; takeMin = ((tid&j)==0)==((tid&k)==0)
  // LDS substeps alternate buffers: write cur, barrier, read cur; next substep
  // writes the other buffer, so its barrier fences this substep's reads.
  int cur = 0;
  for (int k = 2; k <= TSZ; k <<= 1) {
    for (int j = k >> 1; j > 0; j >>= 1) {
      bool asc = ((tid & k) == 0);
      bool takeMin = (((tid & j) == 0) == asc);
      u64 u;
      if (j >= 64) {
        s[cur][tid] = v;
        __syncthreads();
        u = s[cur][tid ^ j];
        cur ^= 1;
      } else {
        u = shfl_xor_u64(v, j);
      }
      v = takeMin ? (v < u ? v : u) : (v > u ? v : u);
    }
  }
  tilesorted[base + tid] = v;
  // packed class indicator of the sorted element (c0 low16, c1 high16);
  // pads (~0ull) sorted to positions >= lim.
  uint32_t v0 = 0;
  if (tid < lim) {
    int idx = (int)(v & 0xffffffffu);
    v0 = (idx < N) ? 1u : (idx < N + E ? (1u << 16) : 0u);
  }
  // inclusive scan: wave shfl scan + cross-wave combine
  uint32_t sv = v0;
  #pragma unroll
  for (int off = 1; off < 64; off <<= 1) {
    uint32_t t = (uint32_t)__shfl_up((int)sv, off, 64);
    if (lane >= off) sv += t;
  }
  __syncthreads();
  if (lane == 63) wsum[wid] = sv;
  __syncthreads();
  if (tid < 16) {
    uint32_t t = wsum[tid];
    #pragma unroll
    for (int off = 1; off < 16; off <<= 1) {
      uint32_t u2 = (uint32_t)__shfl_up((int)t, off, 64);
      if (tid >= off) t += u2;
    }
    wsum[tid] = t;
  }
  __syncthreads();
  uint32_t incl = sv + (wid > 0 ? wsum[wid - 1] : 0u);
  pfx[bid * PSTR + tid] = incl - v0;             // exclusive
  if (tid == TSZ - 1) pfx[bid * PSTR + TSZ] = incl;  // total slot
}

// Rank: block (tile, keyblock). Stage sorted tile + class prefix in LDS; each
// thread binary-searches its key (11 LDS probes) and accumulates its rank with
// one packed atomicAdd. 196 blocks -> latency hidden by occupancy.
__global__ __launch_bounds__(BLK) void k_count(
    const u64* keys, const u64* ts, const uint32_t* pfx, uint32_t* pack,
    int N, int E, int m) {
  __shared__ __align__(16) u64 s[TSZ];
  __shared__ uint32_t sp[TSZ + 1];
  int tid = threadIdx.x;
  int t = blockIdx.x;
  s[tid] = ts[(t << 10) + tid];
  sp[tid] = pfx[t * PSTR + tid];
  if (tid == 0) sp[TSZ] = pfx[t * PSTR + TSZ];
  __syncthreads();
  int ki = blockIdx.y * BLK + tid;
  if (ki >= m) return;
  u64 k0 = keys[ki];
  int cls0 = (ki < N) ? 0 : (ki < N + E ? 1 : 2);
  int lo = 0;
  #pragma unroll
  for (int step = TSZ >> 1; step >= 1; step >>= 1) {
    if (s[lo + step - 1] < k0) lo += step;
  }
  lo += (s[lo] < k0) ? 1 : 0;     // off-by-one fix: count==TSZ case
  uint32_t p = sp[lo];
  uint32_t c0 = p & 0xffffu, c1 = p >> 16;
  uint32_t cc = (cls0 == 0) ? c0 : (cls0 == 1 ? c1 : (uint32_t)lo - c0 - c1);
  atomicAdd(&pack[ki], (cc << 16) | (uint32_t)lo);
}

// Maps: scatter rank data + build relabeled edge lists with closed-form dual
// adjacency. eAB0[er] = primal endpoints as vranks; eAB1[E-1-er] = dual node
// ids (node = F - trank; outer = 0; smaller = elder).
__global__ __launch_bounds__(256) void k_maps(
    const uint32_t* pack, const float* vals,
    float* vsorted, int* vr_to_rank, int* er_to_rank, int* noderank1,
    uint32_t* eAB0, uint32_t* eAB1,
    int N, int E, int F, int m, int W, int H, int nh, int nv, int FH) {
  int i = blockIdx.x * blockDim.x + threadIdx.x;
  if (i >= m) return;
  uint32_t pk = pack[i];
  int rank = (int)(pk & 0xffffu);
  int cls = (int)(pk >> 16);
  vsorted[rank] = vals[i];
  if (i < N) {
    vr_to_rank[cls] = rank;
  } else if (i < N + E) {
    int e = i - N, er = cls;
    er_to_rank[er] = rank;
    int a, b;
    edge_ab(e, W, nh, nv, &a, &b);
    uint32_t va = pack[a] >> 16, vb = pack[b] >> 16;
    eAB0[er] = (va << 16) | vb;
    int tA, tB;
    edge_tri(e, W, H, nh, nv, FH, &tA, &tB);
    uint32_t na = (tA >= 0) ? ((uint32_t)F - (pack[N + E + tA] >> 16)) : 0u;
    uint32_t nb = (tB >= 0) ? ((uint32_t)F - (pack[N + E + tB] >> 16)) : 0u;
    eAB1[E - 1 - er] = (na << 16) | nb;
  } else {
    noderank1[F - cls] = rank;  // dual node id = F - trank (outer = 0)
  }
}

// Range-parallel elder-rule pairing + emit. Block (g, r): graph g (0 = primal
// /dim0, 1 = dual-reversed/dim1), range [P, P+C), C<=27. Prefix DSU via async
// hooking + compression; pre-resolve + ballot-compact candidates; one short
// serial elder-rule UF (<=27 iters); parallel emit. 512 blocks = 2/CU, so
// co-resident blocks' serial tails overlap.
__global__ __launch_bounds__(BLK) void k_pair(
    const uint32_t* eAB0, const uint32_t* eAB1,
    const int* vr_to_rank, const int* er_to_rank, const int* noderank1,
    const float* vsorted, float* out, int N, int E, int F, int C, int m) {
  __shared__ __align__(16) int s_par[FMAXC + 1];
  __shared__ uint32_t s_rc[64];
  __shared__ int s_ci[64];
  __shared__ int2 s_pairs[64];
  __shared__ int s_cnt;
  int tid = threadIdx.x, bid = blockIdx.x;
  int g = bid >> 8;
  int r = bid & (KRANGES - 1);
  int NODES = (g == 0) ? N : (F + 1);
  const uint32_t* eAB = (g == 0) ? eAB0 : eAB1;
  int P = r * C;
  if (P >= E) return;
  int hi = min(P + C, E);
  int nR = hi - P;
  volatile int* vp = s_par;
  for (int x = tid; x < NODES; x += BLK) s_par[x] = x;
  __syncthreads();
  for (int i = tid; i < P; i += BLK) hook(vp, eAB[i]);
  __syncthreads();
  for (int x = tid; x < NODES; x += BLK) {
    int r0 = x;
    while (vp[r0] != r0) r0 = vp[r0];
    s_par[x] = r0;
  }
  __syncthreads();
  // pre-resolve range-edge roots (exact after compression)
  for (int q = tid; q < nR; q += BLK) {
    uint32_t ab = eAB[P + q];
    int ra = s_par[ab >> 16], rb = s_par[ab & 0xffffu];
    s_rc[q] = ((uint32_t)ra << 16) | (uint32_t)rb;
  }
  __syncthreads();
  // wave 0: compact candidates (roots differ), lane 0: serial elder-rule UF
  if (tid < 64) {
    uint32_t rr = (tid < nR) ? s_rc[tid] : 0u;
    int keep = (tid < nR) && ((rr >> 16) != (rr & 0xffffu));
    u64 mask = __ballot(keep);
    if (keep) {
      int idx = __popcll(mask & ((1ull << tid) - 1ull));
      s_rc[idx] = rr;
      s_ci[idx] = tid;
    }
    int kc = __popcll(mask);
    if (tid == 0) {
      int c = 0;
      for (int i = 0; i < kc; ++i) {
        uint32_t rr2 = s_rc[i];
        int x = (int)(rr2 >> 16), y = (int)(rr2 & 0xffffu);
        while (s_par[x] != x) { s_par[x] = s_par[s_par[x]]; x = s_par[x]; }
        while (s_par[y] != y) { s_par[y] = s_par[s_par[y]]; y = s_par[y]; }
        if (x != y) {
          int die = x > y ? x : y, sur = x < y ? x : y;
          s_par[die] = sur;
          s_pairs[c++] = make_int2(die, P + s_ci[i]);
        }
      }
      s_cnt = c;
    }
  }
  __syncthreads();
  int c = s_cnt;
  if (g == 0) {
    for (int q = tid; q < c; q += BLK) {
      int2 pq = s_pairs[q];
      int b = vr_to_rank[pq.x], d = er_to_rank[pq.y];
      out[2 * b] = vsorted[b];
      out[2 * b + 1] = vsorted[d];
    }
    if (r == 0 && tid == 0) {
      // essential dim-0 class: rank 0 birth, death = fmax (rank m-1)
      out[0] = vsorted[0];
      out[1] = vsorted[m - 1];
    }
  } else {
    float* o1 = out + 2 * (size_t)m;
    for (int q = tid; q < c; q += BLK) {
      int2 pq = s_pairs[q];
      int er = E - 1 - pq.y;
      int b = er_to_rank[er], d = noderank1[pq.x];
      o1[2 * b] = vsorted[b];
      o1[2 * b + 1] = vsorted[d];
    }
  }
}

extern "C" void kernel_launch(void* const* d_in, const int* in_sizes, int n_in,
                              void* d_out, int out_size, void* d_ws, size_t ws_size,
                              hipStream_t stream) {
  const float* img = (const float*)d_in[0];
  int N = in_sizes[0];
  int E = in_sizes[1] / 2;
  int F = in_sizes[2] / 3;
  int m = N + E + F;
  int C = (E + KRANGES - 1) / KRANGES;
  int W = (int)(sqrt((double)N) + 0.5);
  int H = N / W;
  int nh = H * (W - 1);
  int nv = (H - 1) * W;
  int FH = (H - 1) * (W - 1);
  int NT = (m + TSZ - 1) / TSZ;
  float* out = (float*)d_out;

  char* p = (char*)d_ws;
  auto alloc = [&](size_t bytes) { char* r = p; p += (bytes + 255) & ~(size_t)255; return r; };
  u64* keys        = (u64*)alloc((size_t)NT * TSZ * 8);
  u64* tilesorted  = (u64*)alloc((size_t)NT * TSZ * 8);
  uint32_t* pfx    = (uint32_t*)alloc((size_t)NT * PSTR * 4);
  float* vals      = (float*)alloc((size_t)m * 4);
  float* vsorted   = (float*)alloc((size_t)m * 4);
  uint32_t* pack   = (uint32_t*)alloc((size_t)m * 4);
  int* vr_to_rank  = (int*)alloc((size_t)N * 4);
  int* er_to_rank  = (int*)alloc((size_t)E * 4);
  int* noderank1   = (int*)alloc((size_t)(F + 1) * 4);
  uint32_t* eAB0   = (uint32_t*)alloc((size_t)E * 4);
  uint32_t* eAB1   = (uint32_t*)alloc((size_t)E * 4);
  (void)ws_size; (void)n_in;

  k_prep<<<NT, BLK, 0, stream>>>(img, vals, keys, tilesorted, pfx, pack, out,
                                 N, E, F, m, W, H, nh, nv, FH, out_size, NT);
  dim3 cg(NT, NT);
  k_count<<<cg, BLK, 0, stream>>>(keys, tilesorted, pfx, pack, N, E, m);
  k_maps<<<(m + 255) / 256, 256, 0, stream>>>(pack, vals, vsorted,
                                              vr_to_rank, er_to_rank, noderank1,
                                              eAB0, eAB1, N, E, F, m, W, H, nh, nv, FH);
  k_pair<<<2 * KRANGES, BLK, 0, stream>>>(eAB0, eAB1, vr_to_rank, er_to_rank,
                                          noderank1, vsorted, out, N, E, F, C, m);
}